// Round 6
// baseline (371.862 us; speedup 1.0000x reference)
//
#include <hip/hip_runtime.h>
#include <hip/hip_bf16.h>

// Problem constants
#define M_DIM 2048
#define K_DIM 50000
#define N_DIM 256
#define L_PATH 32
// GEMM tiling
#define BMt 128
#define BNt 256
#define BKt 64
#define TOTAL_KSTEPS 782      // ceil(50000/64)
#define KSPLIT 16
#define STEPS_PER_SPLIT 49    // ceil(782/16)
#define MTILES 16             // 2048/128

typedef __bf16 bf16x8 __attribute__((ext_vector_type(8)));
typedef __bf16 bf16x4 __attribute__((ext_vector_type(4)));
typedef float f32x4 __attribute__((ext_vector_type(4)));
typedef float fx4 __attribute__((ext_vector_type(4)));

struct StageRegs { fx4 a[4]; fx4 w[8]; };

// x = A (2048x50000) * W^T (W is 256x50000), split-K. bf16 MFMA, fp32 acc.
// Reg-staged bf16-LDS pipeline (R4 structure) with the VGPR cap LIFTED:
// R2/R4 showed the compiler pins 128 arch-VGPRs for 512-thr blocks by default
// and spills the stage registers (548MB scratch). __launch_bounds__(512,1)
// allows up to ~256 VGPR at the same 2-waves/SIMD occupancy (m69).
// Per step: issue(t+2 -> free set); compute(LDS[p]); pack(inflight -> LDS[p^1])
// [compiler emits counted vmcnt(12): t+2's loads stay in flight across the
// barrier]; s_waitcnt lgkmcnt(0); s_barrier.
__global__ __launch_bounds__(512, 1)
void gemm_bf16_splitk(const float* __restrict__ A, const float* __restrict__ W,
                      float* __restrict__ outp, int use_atomic)
{
  // Swizzled bf16 LDS tiles: (row, col) at row*BKt + XOR on 8-col/16B granule
  __shared__ __align__(16) unsigned short sA[2][BMt * BKt];   // 2 x 16 KB
  __shared__ __align__(16) unsigned short sW[2][BNt * BKt];   // 2 x 32 KB

  // XCD-bijective block swizzle (gridDim.x = 256, divisible by 8).
  int bid = blockIdx.x;
  int per = gridDim.x >> 3;
  int Lw = (bid & 7) * per + (bid >> 3);
  int mtile = Lw & (MTILES - 1);
  int ksp = Lw >> 4;                 // MTILES == 16

  int m0 = mtile * BMt;
  int s0 = ksp * STEPS_PER_SPLIT;
  int s1 = s0 + STEPS_PER_SPLIT;
  if (s1 > TOTAL_KSTEPS) s1 = TOTAL_KSTEPS;

  int tid = threadIdx.x;
  int wid = tid >> 6, lane = tid & 63;
  int wm = wid >> 2, wn = wid & 3;          // wave grid 2 x 4, each wave 64x64
  int l15 = lane & 15, l4 = lane >> 4;

  // Coalesced staging: 16 lanes x 16B cover one 64-col row chunk (256 B);
  // per load instruction a wave reads 4 full contiguous rows (1 KB).
  int rowt = tid >> 4;   // 0..31
  int chk  = tid & 15;   // 16B chunk within row (4 fp32 cols)
  const float* Ab = A + (size_t)(m0 + rowt) * K_DIM + chk * 4;
  const float* Wb = W + (size_t)rowt * K_DIM + chk * 4;

  // Per-i LDS write offsets (element index): cols [chk*4, chk*4+4) at swizzled granule
  int offA[4], offW[8];
#pragma unroll
  for (int i = 0; i < 4; ++i) {
    int r = i * 32 + rowt;
    offA[i] = r * BKt + ((((chk >> 1) ^ (r & 7)) << 3) + (chk & 1) * 4);
  }
#pragma unroll
  for (int i = 0; i < 8; ++i) {
    int r = i * 32 + rowt;
    offW[i] = r * BKt + ((((chk >> 1) ^ (r & 7)) << 3) + (chk & 1) * 4);
  }

  StageRegs r0, r1;

  auto issue = [&](StageRegs& R, int s) {
    size_t kb = (size_t)s * BKt;
    const float* ap = Ab + kb;
    const float* wp = Wb + kb;
    int k = s * BKt + chk * 4;
    if (k + 4 <= K_DIM) {
#pragma unroll
      for (int i = 0; i < 4; ++i) R.a[i] = *reinterpret_cast<const fx4*>(ap + (size_t)i * 32 * K_DIM);
#pragma unroll
      for (int i = 0; i < 8; ++i) R.w[i] = *reinterpret_cast<const fx4*>(wp + (size_t)i * 32 * K_DIM);
    } else {
#pragma unroll
      for (int i = 0; i < 4; ++i) {
        fx4 f;
#pragma unroll
        for (int e = 0; e < 4; ++e) f[e] = (k + e < K_DIM) ? ap[(size_t)i * 32 * K_DIM + e] : 0.f;
        R.a[i] = f;
      }
#pragma unroll
      for (int i = 0; i < 8; ++i) {
        fx4 f;
#pragma unroll
        for (int e = 0; e < 4; ++e) f[e] = (k + e < K_DIM) ? wp[(size_t)i * 32 * K_DIM + e] : 0.f;
        R.w[i] = f;
      }
    }
  };

  // fp32 -> bf16 via casts so the compiler emits v_cvt_pk_bf16_f32 (RTNE).
  auto pack = [&](StageRegs& R, int p) {
#pragma unroll
    for (int i = 0; i < 4; ++i) {
      bf16x4 h;
      h[0] = (__bf16)R.a[i][0]; h[1] = (__bf16)R.a[i][1];
      h[2] = (__bf16)R.a[i][2]; h[3] = (__bf16)R.a[i][3];
      *reinterpret_cast<bf16x4*>(&sA[p][offA[i]]) = h;
    }
#pragma unroll
    for (int i = 0; i < 8; ++i) {
      bf16x4 h;
      h[0] = (__bf16)R.w[i][0]; h[1] = (__bf16)R.w[i][1];
      h[2] = (__bf16)R.w[i][2]; h[3] = (__bf16)R.w[i][3];
      *reinterpret_cast<bf16x4*>(&sW[p][offW[i]]) = h;
    }
  };

  f32x4 acc[4][4] = {};

  auto compute = [&](int p) {
#pragma unroll
    for (int kk = 0; kk < 2; ++kk) {
      bf16x8 afr[4], bfr[4];
      int c = kk * 32 + l4 * 8;
#pragma unroll
      for (int mf = 0; mf < 4; ++mf) {
        int r = wm * 64 + mf * 16 + l15;
        afr[mf] = *reinterpret_cast<const bf16x8*>(&sA[p][r * BKt + (c ^ ((r & 7) << 3))]);
      }
#pragma unroll
      for (int nf = 0; nf < 4; ++nf) {
        int r = wn * 64 + nf * 16 + l15;
        bfr[nf] = *reinterpret_cast<const bf16x8*>(&sW[p][r * BKt + (c ^ ((r & 7) << 3))]);
      }
#pragma unroll
      for (int mf = 0; mf < 4; ++mf)
#pragma unroll
        for (int nf = 0; nf < 4; ++nf)
          acc[mf][nf] = __builtin_amdgcn_mfma_f32_16x16x32_bf16(afr[mf], bfr[nf], acc[mf][nf], 0, 0, 0);
    }
  };

#define WB() do { asm volatile("s_waitcnt lgkmcnt(0)" ::: "memory"); \
                  __builtin_amdgcn_s_barrier(); } while (0)

  // Prologue: tile s0 -> regs r0; tile s0+1 loads in flight (r1); pack s0 to LDS[0].
  issue(r0, s0);
  if (s0 + 1 < s1) issue(r1, s0 + 1);
  pack(r0, 0);           // counted vmcnt: waits r0 only, r1 stays in flight
  WB();

  int t = s0, p = 0;
  for (;;) {
    // phase A: inflight = r1 (tile t+1), free = r0
    if (t + 1 >= s1) { compute(p); break; }
    if (t + 2 < s1) issue(r0, t + 2);
    compute(p);
    pack(r1, p ^ 1);     // counted vmcnt: r0's loads survive the barrier
    WB();
    ++t; p ^= 1;
    // phase B: inflight = r0, free = r1
    if (t + 1 >= s1) { compute(p); break; }
    if (t + 2 < s1) issue(r1, t + 2);
    compute(p);
    pack(r0, p ^ 1);
    WB();
    ++t; p ^= 1;
  }
#undef WB

  // epilogue: C/D layout col = lane&15, row = (lane>>4)*4 + j
  if (use_atomic) {
#pragma unroll
    for (int mf = 0; mf < 4; ++mf)
#pragma unroll
      for (int nf = 0; nf < 4; ++nf)
#pragma unroll
        for (int j = 0; j < 4; ++j) {
          int row = m0 + wm * 64 + mf * 16 + l4 * 4 + j;
          int col = wn * 64 + nf * 16 + l15;
          atomicAdd(&outp[(size_t)row * N_DIM + col], acc[mf][nf][j]);
        }
  } else {
    float* part = outp + (size_t)ksp * (M_DIM * N_DIM);
#pragma unroll
    for (int mf = 0; mf < 4; ++mf)
#pragma unroll
      for (int nf = 0; nf < 4; ++nf)
#pragma unroll
        for (int j = 0; j < 4; ++j) {
          int row = m0 + wm * 64 + mf * 16 + l4 * 4 + j;
          int col = wn * 64 + nf * 16 + l15;
          part[(size_t)row * N_DIM + col] = acc[mf][nf][j];
        }
  }
}

// One block (256 thr = 4 waves) per sample: reduce split-K partials for this row
// into LDS, gather path vecs, dot with x, BCE.
__global__ __launch_bounds__(256)
void loss_kernel(const float* __restrict__ part, int nparts,
                 const float* __restrict__ cls_w,
                 const int* __restrict__ nodes, const int* __restrict__ codes,
                 const int* __restrict__ lens, float* __restrict__ per_sample)
{
  int i = blockIdx.x;
  int tid = threadIdx.x;
  __shared__ float s_x[N_DIM];
  {
    float s = 0.f;
    for (int k = 0; k < nparts; ++k)
      s += part[(size_t)k * (M_DIM * N_DIM) + (size_t)i * N_DIM + tid];
    s_x[tid] = s;
  }
  __syncthreads();

  int wid = tid >> 6, lane = tid & 63;
  __shared__ float s_logit[L_PATH];
  fx4 xv = *reinterpret_cast<const fx4*>(&s_x[lane * 4]);
#pragma unroll
  for (int j = 0; j < 8; ++j) {
    int pos = wid * 8 + j;
    int node = nodes[i * L_PATH + pos];
    fx4 cv = *reinterpret_cast<const fx4*>(&cls_w[(size_t)node * N_DIM + lane * 4]);
    float d = xv[0] * cv[0] + xv[1] * cv[1] + xv[2] * cv[2] + xv[3] * cv[3];
#pragma unroll
    for (int s = 32; s > 0; s >>= 1) d += __shfl_xor(d, s);
    if (lane == 0) s_logit[pos] = d;
  }
  __syncthreads();
  if (wid == 0) {
    int len = lens[i];
    int lenc = len < 1 ? 1 : len;
    float v = 0.f;
    if (lane < L_PATH && lane < lenc) {
      float z = s_logit[lane];
      float y = (float)codes[i * L_PATH + lane];
      v = fmaxf(z, 0.f) - z * y + log1pf(expf(-fabsf(z)));
    }
#pragma unroll
    for (int s = 32; s > 0; s >>= 1) v += __shfl_xor(v, s);
    if (lane == 0) per_sample[i] = v / (float)lenc;
  }
}

__global__ __launch_bounds__(256)
void final_reduce(const float* __restrict__ ps, float* __restrict__ out) {
  int tid = threadIdx.x;
  float s = 0.f;
#pragma unroll
  for (int i = 0; i < M_DIM / 256; ++i) s += ps[tid + i * 256];
  __shared__ float sm[4];
#pragma unroll
  for (int sh = 32; sh > 0; sh >>= 1) s += __shfl_xor(s, sh);
  if ((tid & 63) == 0) sm[tid >> 6] = s;
  __syncthreads();
  if (tid == 0) out[0] = (sm[0] + sm[1] + sm[2] + sm[3]) * (1.0f / (float)M_DIM);
}

extern "C" void kernel_launch(void* const* d_in, const int* in_sizes, int n_in,
                              void* d_out, int out_size, void* d_ws, size_t ws_size,
                              hipStream_t stream) {
  const float* A     = (const float*)d_in[0];   // inputs_vector [2048, 50000]
  const float* W     = (const float*)d_in[1];   // W [256, 50000]
  const float* cls_w = (const float*)d_in[2];   // [49999, 256]
  const int* nodes   = (const int*)d_in[3];     // [2048, 32]
  const int* codes   = (const int*)d_in[4];     // [2048, 32]
  const int* lens    = (const int*)d_in[5];     // [2048]
  float* out = (float*)d_out;

  char* ws = (char*)d_ws;
  const size_t XBYTES = (size_t)M_DIM * N_DIM * sizeof(float);   // 2 MB
  float* per_sample = (float*)ws;                                // 8 KB
  float* x          = (float*)(ws + (size_t)(64u << 10));        // 2 MB (atomic path)
  float* partials   = (float*)(ws + (size_t)(4u << 20));         // KSPLIT * 2 MB

  int use_atomic = (ws_size < (size_t)(4u << 20) + (size_t)KSPLIT * XBYTES) ? 1 : 0;

  if (use_atomic) {
    hipMemsetAsync(x, 0, XBYTES, stream);
    gemm_bf16_splitk<<<dim3(MTILES * KSPLIT), dim3(512), 0, stream>>>(A, W, x, 1);
    loss_kernel<<<dim3(M_DIM), dim3(256), 0, stream>>>(x, 1, cls_w, nodes, codes, lens, per_sample);
  } else {
    gemm_bf16_splitk<<<dim3(MTILES * KSPLIT), dim3(512), 0, stream>>>(A, W, partials, 0);
    loss_kernel<<<dim3(M_DIM), dim3(256), 0, stream>>>(partials, KSPLIT, cls_w, nodes, codes, lens, per_sample);
  }
  final_reduce<<<dim3(1), dim3(256), 0, stream>>>(per_sample, out);
}

// Round 7
// 153.537 us; speedup vs baseline: 2.4220x; 2.4220x over previous
//
#include <hip/hip_runtime.h>
#include <hip/hip_bf16.h>

// Problem constants
#define M_DIM 2048
#define K_DIM 50000
#define N_DIM 256
#define L_PATH 32
// GEMM tiling
#define BMt 128
#define BNt 256
#define BKt 64
#define TOTAL_KSTEPS 782      // ceil(50000/64)
#define KSPLIT 16
#define STEPS_PER_SPLIT 49    // ceil(782/16)
#define MTILES 16             // 2048/128

typedef __bf16 bf16x8 __attribute__((ext_vector_type(8)));
typedef __bf16 bf16x4 __attribute__((ext_vector_type(4)));
typedef float f32x4 __attribute__((ext_vector_type(4)));
typedef float fx4 __attribute__((ext_vector_type(4)));

// x = A (2048x50000) * W^T (W is 256x50000), split-K. bf16 MFMA, fp32 acc.
// SINGLE stage register set (48 VGPR) -- R3/R4/R6 proved two sets exceed the
// 128-VGPR allocator cap for 512-thread blocks and spill (548MB scratch, 2.3x).
// Counted-vmcnt pipeline, one raw barrier per step:
//   compute(LDS[p]); pack(stage -> LDS[p^1]) [per-write counted vmcnt];
//   issue(t+2 -> stage); s_waitcnt lgkmcnt(0); s_barrier.
// Issued loads stay in flight ACROSS the barrier and drain during the next
// step's compute -- unlike __syncthreads() which drains vmcnt(0) every step.
__global__ __launch_bounds__(512)
void gemm_bf16_splitk(const float* __restrict__ A, const float* __restrict__ W,
                      float* __restrict__ outp, int use_atomic)
{
  // Swizzled bf16 LDS tiles: (row, col) at row*BKt + XOR on 8-col/16B granule
  __shared__ __align__(16) unsigned short sA[2][BMt * BKt];   // 2 x 16 KB
  __shared__ __align__(16) unsigned short sW[2][BNt * BKt];   // 2 x 32 KB

  // XCD-bijective block swizzle (gridDim.x = 256, divisible by 8):
  // XCD x gets ksp {2x, 2x+1} -> its W chunks (6.4MB) mostly L2-resident.
  int bid = blockIdx.x;
  int per = gridDim.x >> 3;
  int Lw = (bid & 7) * per + (bid >> 3);
  int mtile = Lw & (MTILES - 1);
  int ksp = Lw >> 4;                 // MTILES == 16

  int m0 = mtile * BMt;
  int s0 = ksp * STEPS_PER_SPLIT;
  int s1 = s0 + STEPS_PER_SPLIT;
  if (s1 > TOTAL_KSTEPS) s1 = TOTAL_KSTEPS;

  int tid = threadIdx.x;
  int wid = tid >> 6, lane = tid & 63;
  int wm = wid >> 2, wn = wid & 3;          // wave grid 2 x 4, each wave 64x64
  int l15 = lane & 15, l4 = lane >> 4;

  // Coalesced staging: 16 lanes x 16B cover one 64-col row chunk (256 B);
  // per load instruction a wave reads 4 full contiguous rows (1 KB).
  int rowt = tid >> 4;   // 0..31
  int chk  = tid & 15;   // 16B chunk within row (4 fp32 cols)
  const float* Ab = A + (size_t)(m0 + rowt) * K_DIM + chk * 4;
  const float* Wb = W + (size_t)rowt * K_DIM + chk * 4;

  // Per-i LDS write offsets (element index): cols [chk*4, chk*4+4) at swizzled granule
  int offA[4], offW[8];
#pragma unroll
  for (int i = 0; i < 4; ++i) {
    int r = i * 32 + rowt;
    offA[i] = r * BKt + ((((chk >> 1) ^ (r & 7)) << 3) + (chk & 1) * 4);
  }
#pragma unroll
  for (int i = 0; i < 8; ++i) {
    int r = i * 32 + rowt;
    offW[i] = r * BKt + ((((chk >> 1) ^ (r & 7)) << 3) + (chk & 1) * 4);
  }

  // SINGLE stage set: 12 x fx4 = 48 VGPR.
  fx4 ra[4], rw[8];

  auto issue = [&](int s) {
    size_t kb = (size_t)s * BKt;
    const float* ap = Ab + kb;
    const float* wp = Wb + kb;
    int k = s * BKt + chk * 4;
    if (k + 4 <= K_DIM) {
#pragma unroll
      for (int i = 0; i < 4; ++i) ra[i] = *reinterpret_cast<const fx4*>(ap + (size_t)i * 32 * K_DIM);
#pragma unroll
      for (int i = 0; i < 8; ++i) rw[i] = *reinterpret_cast<const fx4*>(wp + (size_t)i * 32 * K_DIM);
    } else {
#pragma unroll
      for (int i = 0; i < 4; ++i) {
        fx4 f;
#pragma unroll
        for (int e = 0; e < 4; ++e) f[e] = (k + e < K_DIM) ? ap[(size_t)i * 32 * K_DIM + e] : 0.f;
        ra[i] = f;
      }
#pragma unroll
      for (int i = 0; i < 8; ++i) {
        fx4 f;
#pragma unroll
        for (int e = 0; e < 4; ++e) f[e] = (k + e < K_DIM) ? wp[(size_t)i * 32 * K_DIM + e] : 0.f;
        rw[i] = f;
      }
    }
  };

  // fp32 -> bf16 via casts (compiler emits v_cvt_pk_bf16_f32, RTNE).
  // Each ds_write depends only on its own loads -> compiler emits counted
  // vmcnt(11), vmcnt(10), ... interleaved, never draining the later tile.
  auto pack = [&](int p) {
#pragma unroll
    for (int i = 0; i < 4; ++i) {
      bf16x4 h;
      h[0] = (__bf16)ra[i][0]; h[1] = (__bf16)ra[i][1];
      h[2] = (__bf16)ra[i][2]; h[3] = (__bf16)ra[i][3];
      *reinterpret_cast<bf16x4*>(&sA[p][offA[i]]) = h;
    }
#pragma unroll
    for (int i = 0; i < 8; ++i) {
      bf16x4 h;
      h[0] = (__bf16)rw[i][0]; h[1] = (__bf16)rw[i][1];
      h[2] = (__bf16)rw[i][2]; h[3] = (__bf16)rw[i][3];
      *reinterpret_cast<bf16x4*>(&sW[p][offW[i]]) = h;
    }
  };

  f32x4 acc[4][4] = {};

  auto compute = [&](int p) {
#pragma unroll
    for (int kk = 0; kk < 2; ++kk) {
      bf16x8 afr[4], bfr[4];
      int c = kk * 32 + l4 * 8;
#pragma unroll
      for (int mf = 0; mf < 4; ++mf) {
        int r = wm * 64 + mf * 16 + l15;
        afr[mf] = *reinterpret_cast<const bf16x8*>(&sA[p][r * BKt + (c ^ ((r & 7) << 3))]);
      }
#pragma unroll
      for (int nf = 0; nf < 4; ++nf) {
        int r = wn * 64 + nf * 16 + l15;
        bfr[nf] = *reinterpret_cast<const bf16x8*>(&sW[p][r * BKt + (c ^ ((r & 7) << 3))]);
      }
#pragma unroll
      for (int mf = 0; mf < 4; ++mf)
#pragma unroll
        for (int nf = 0; nf < 4; ++nf)
          acc[mf][nf] = __builtin_amdgcn_mfma_f32_16x16x32_bf16(afr[mf], bfr[nf], acc[mf][nf], 0, 0, 0);
    }
  };

#define WB() do { asm volatile("s_waitcnt lgkmcnt(0)" ::: "memory"); \
                  __builtin_amdgcn_s_barrier(); } while (0)

  // Prologue: tile s0 staged to LDS[0]; tile s0+1's loads left in flight.
  issue(s0);
  pack(0);
  if (s0 + 1 < s1) issue(s0 + 1);
  WB();

  int p = 0;
  for (int t = s0; t < s1; ++t) {
    compute(p);                    // reads LDS[p]; overlaps in-flight loads' drain
    if (t + 1 < s1) {
      pack(p ^ 1);                 // counted vmcnt waits for tile t+1 only
      if (t + 2 < s1) issue(t + 2);  // crosses the barrier in flight
      WB();
    }
    p ^= 1;
  }
#undef WB

  // epilogue: C/D layout col = lane&15, row = (lane>>4)*4 + j
  if (use_atomic) {
#pragma unroll
    for (int mf = 0; mf < 4; ++mf)
#pragma unroll
      for (int nf = 0; nf < 4; ++nf)
#pragma unroll
        for (int j = 0; j < 4; ++j) {
          int row = m0 + wm * 64 + mf * 16 + l4 * 4 + j;
          int col = wn * 64 + nf * 16 + l15;
          atomicAdd(&outp[(size_t)row * N_DIM + col], acc[mf][nf][j]);
        }
  } else {
    float* part = outp + (size_t)ksp * (M_DIM * N_DIM);
#pragma unroll
    for (int mf = 0; mf < 4; ++mf)
#pragma unroll
      for (int nf = 0; nf < 4; ++nf)
#pragma unroll
        for (int j = 0; j < 4; ++j) {
          int row = m0 + wm * 64 + mf * 16 + l4 * 4 + j;
          int col = wn * 64 + nf * 16 + l15;
          part[(size_t)row * N_DIM + col] = acc[mf][nf][j];
        }
  }
}

// One block (256 thr = 4 waves) per sample: reduce split-K partials for this row
// into LDS, gather path vecs, dot with x, BCE.
__global__ __launch_bounds__(256)
void loss_kernel(const float* __restrict__ part, int nparts,
                 const float* __restrict__ cls_w,
                 const int* __restrict__ nodes, const int* __restrict__ codes,
                 const int* __restrict__ lens, float* __restrict__ per_sample)
{
  int i = blockIdx.x;
  int tid = threadIdx.x;
  __shared__ float s_x[N_DIM];
  {
    float s = 0.f;
    for (int k = 0; k < nparts; ++k)
      s += part[(size_t)k * (M_DIM * N_DIM) + (size_t)i * N_DIM + tid];
    s_x[tid] = s;
  }
  __syncthreads();

  int wid = tid >> 6, lane = tid & 63;
  __shared__ float s_logit[L_PATH];
  fx4 xv = *reinterpret_cast<const fx4*>(&s_x[lane * 4]);
#pragma unroll
  for (int j = 0; j < 8; ++j) {
    int pos = wid * 8 + j;
    int node = nodes[i * L_PATH + pos];
    fx4 cv = *reinterpret_cast<const fx4*>(&cls_w[(size_t)node * N_DIM + lane * 4]);
    float d = xv[0] * cv[0] + xv[1] * cv[1] + xv[2] * cv[2] + xv[3] * cv[3];
#pragma unroll
    for (int s = 32; s > 0; s >>= 1) d += __shfl_xor(d, s);
    if (lane == 0) s_logit[pos] = d;
  }
  __syncthreads();
  if (wid == 0) {
    int len = lens[i];
    int lenc = len < 1 ? 1 : len;
    float v = 0.f;
    if (lane < L_PATH && lane < lenc) {
      float z = s_logit[lane];
      float y = (float)codes[i * L_PATH + lane];
      v = fmaxf(z, 0.f) - z * y + log1pf(expf(-fabsf(z)));
    }
#pragma unroll
    for (int s = 32; s > 0; s >>= 1) v += __shfl_xor(v, s);
    if (lane == 0) per_sample[i] = v / (float)lenc;
  }
}

__global__ __launch_bounds__(256)
void final_reduce(const float* __restrict__ ps, float* __restrict__ out) {
  int tid = threadIdx.x;
  float s = 0.f;
#pragma unroll
  for (int i = 0; i < M_DIM / 256; ++i) s += ps[tid + i * 256];
  __shared__ float sm[4];
#pragma unroll
  for (int sh = 32; sh > 0; sh >>= 1) s += __shfl_xor(s, sh);
  if ((tid & 63) == 0) sm[tid >> 6] = s;
  __syncthreads();
  if (tid == 0) out[0] = (sm[0] + sm[1] + sm[2] + sm[3]) * (1.0f / (float)M_DIM);
}

extern "C" void kernel_launch(void* const* d_in, const int* in_sizes, int n_in,
                              void* d_out, int out_size, void* d_ws, size_t ws_size,
                              hipStream_t stream) {
  const float* A     = (const float*)d_in[0];   // inputs_vector [2048, 50000]
  const float* W     = (const float*)d_in[1];   // W [256, 50000]
  const float* cls_w = (const float*)d_in[2];   // [49999, 256]
  const int* nodes   = (const int*)d_in[3];     // [2048, 32]
  const int* codes   = (const int*)d_in[4];     // [2048, 32]
  const int* lens    = (const int*)d_in[5];     // [2048]
  float* out = (float*)d_out;

  char* ws = (char*)d_ws;
  const size_t XBYTES = (size_t)M_DIM * N_DIM * sizeof(float);   // 2 MB
  float* per_sample = (float*)ws;                                // 8 KB
  float* x          = (float*)(ws + (size_t)(64u << 10));        // 2 MB (atomic path)
  float* partials   = (float*)(ws + (size_t)(4u << 20));         // KSPLIT * 2 MB

  int use_atomic = (ws_size < (size_t)(4u << 20) + (size_t)KSPLIT * XBYTES) ? 1 : 0;

  if (use_atomic) {
    hipMemsetAsync(x, 0, XBYTES, stream);
    gemm_bf16_splitk<<<dim3(MTILES * KSPLIT), dim3(512), 0, stream>>>(A, W, x, 1);
    loss_kernel<<<dim3(M_DIM), dim3(256), 0, stream>>>(x, 1, cls_w, nodes, codes, lens, per_sample);
  } else {
    gemm_bf16_splitk<<<dim3(MTILES * KSPLIT), dim3(512), 0, stream>>>(A, W, partials, 0);
    loss_kernel<<<dim3(M_DIM), dim3(256), 0, stream>>>(partials, KSPLIT, cls_w, nodes, codes, lens, per_sample);
  }
  final_reduce<<<dim3(1), dim3(256), 0, stream>>>(per_sample, out);
}